// Round 3
// baseline (646.706 us; speedup 1.0000x reference)
//
#include <hip/hip_runtime.h>
#include <math.h>

// Problem constants (B=128, V=784, D=512, 3 cases)
#define B_   128
#define V_   784
#define D_   512
#define M_   384      // 3*B rows (case-major: m = c*128 + b)
#define NCH  7        // ceil(784/128) column chunks
#define NBLK (3 * NCH * B_)   // 2688 gemm blocks = 8 XCDs * 3 * 112

typedef __attribute__((ext_vector_type(8))) short short8;   // 8 bf16 (4 VGPRs)
typedef __attribute__((ext_vector_type(4))) float f32x4;    // MFMA accumulator

// fp32 -> bf16 round-to-nearest-even (finite inputs; sign-safe bit trick)
__device__ __forceinline__ ushort f2bf(float x) {
  uint u = __float_as_uint(x);
  u += 0x7fff + ((u >> 16) & 1);
  return (ushort)(u >> 16);
}
__device__ __forceinline__ float bf2f(ushort h) {
  return __uint_as_float((uint)h << 16);
}

// Swizzled element index into a [128][64] ushort LDS tile.
// byte ^= ((row&7)<<4)  <=>  elem ^= ((row&7)<<3). Preserves 8B/16B chunk
// integrity (XOR bits >= 3), spreads the 128B row stride across 8 16B slots
// (T2 / Guideline 4) -> ds_read_b128 column reads are conflict-free.
__device__ __forceinline__ int swz(int row, int col) {
  return (row * 64 + col) ^ ((row & 7) << 3);
}

__device__ __forceinline__ short8 ldfrag(const ushort* base, int row, int col) {
  union { uint4 u; short8 s; } t;
  t.u = *(const uint4*)(base + swz(row, col));
  return t.s;
}

// ---------------------------------------------------------------------------
// Kernel 0: precompute lan as bf16 hi/lo, already in the swizzled per-(c,kb)
// tile layout the GEMM's LDS expects. lanbf[(c*8+kb)*2*8192 + {0|8192} + swz].
// 3*8*2*8192 ushorts = 786 KB; runs once per launch, L2-resident afterwards.
// ---------------------------------------------------------------------------
__global__ __launch_bounds__(256)
void prep_lan(const float* __restrict__ lan, ushort* __restrict__ lanbf) {
  const int c = blockIdx.x, kb = blockIdx.y, t = threadIdx.x;
  const size_t base = ((size_t)(c * 8 + kb) * 2) * 8192;
  #pragma unroll
  for (int i = 0; i < 8; i++) {
    const int f = t + 256 * i;       // float4 id 0..2047
    const int row = f >> 4;          // b
    const int col = (f & 15) * 4;    // k within the 64-wide tile
    const float4 v =
        *(const float4*)(lan + (size_t)(row * 3 + c) * D_ + kb * 64 + col);
    ushort4 h, l;
    h.x = f2bf(v.x); l.x = f2bf(v.x - bf2f(h.x));
    h.y = f2bf(v.y); l.y = f2bf(v.y - bf2f(h.y));
    h.z = f2bf(v.z); l.z = f2bf(v.z - bf2f(h.z));
    h.w = f2bf(v.w); l.w = f2bf(v.w - bf2f(h.w));
    const int e = swz(row, col);
    *(ushort4*)&lanbf[base + e] = h;
    *(ushort4*)&lanbf[base + 8192 + e] = l;
  }
}

// ---------------------------------------------------------------------------
// Kernel 1: sim GEMM (MFMA, bf16 hi/lo split) fused with per-chunk top-2.
// Fixed (a, c): S[b, v] = lan_c[b] . vis[a, v], K=512, tile 128x128, BK=64.
// 256 threads = 4 waves; wave (wr,wc) owns a 64x64 quadrant.
// S = Ah*Bh + Ah*Bl + Al*Bh  (fp32-accurate to ~2^-18).
// Grid: 2688 linear, decoded so the 3 case-blocks of one (nch,a) vis tile get
// consecutive slots on the SAME XCD (id%8 round-robin) -> tile read once into
// that XCD's L2, reused 3x.
// ---------------------------------------------------------------------------
__global__ __launch_bounds__(256)
void gemm_top2(const float* __restrict__ vis, const ushort* __restrict__ lanbf,
               float* __restrict__ pv1, float* __restrict__ pv2,
               int* __restrict__ pi1) {
  // --- XCD-grouping decode (bijective on [0,2688): 2688 = 8 * 3 * 112) ---
  const int id = blockIdx.x;
  const int xcd = id & 7;
  const int slot = id >> 3;        // 0..335
  const int q = slot / 3;          // 0..111
  const int c = slot - 3 * q;      // case 0..2 (consecutive slots, same XCD)
  const int g = (q << 3) | xcd;    // 0..895 = (a, nch) group
  const int a = g / NCH;
  const int nch = g - NCH * a;

  const int t = threadIdx.x;
  const int lane = t & 63, wid = t >> 6;
  const int tx = lane & 15, qq = lane >> 4;
  const int wr = wid >> 1, wc = wid & 1;

  __shared__ __align__(16) ushort Ah[128 * 64], Al[128 * 64];
  __shared__ __align__(16) ushort Bh[128 * 64], Bl[128 * 64];
  __shared__ float p1buf[2][128], p2buf[2][128];
  __shared__ int   i1buf[2][128];

  f32x4 acc[4][4];
  const f32x4 zz = {0.f, 0.f, 0.f, 0.f};
  #pragma unroll
  for (int m = 0; m < 4; m++)
    #pragma unroll
    for (int n = 0; n < 4; n++) acc[m][n] = zz;

  const int v0 = nch * 128;
  const float* visA = vis + (size_t)a * V_ * D_;

  for (int kb = 0; kb < 8; kb++) {
    const int k0 = kb * 64;
    // A: plain 16B copies of the precomputed swizzled bf16 tiles (no math).
    const ushort* Asrc = lanbf + ((size_t)(c * 8 + kb) * 2) * 8192;
    #pragma unroll
    for (int i = 0; i < 4; i++) {
      const int e = (t + 256 * i) * 8;   // 8-ushort (16B) chunk
      *(uint4*)&Ah[e] = *(const uint4*)&Asrc[e];
      *(uint4*)&Al[e] = *(const uint4*)&Asrc[8192 + e];
    }
    // B: stage 128x64 fp32 of vis, convert to hi/lo bf16, swizzled.
    #pragma unroll
    for (int i = 0; i < 8; i++) {
      const int f = t + 256 * i;       // float4 id 0..2047
      const int row = f >> 4;
      const int col = (f & 15) * 4;
      const int vrow = v0 + row;
      float4 vb = make_float4(0.f, 0.f, 0.f, 0.f);
      if (vrow < V_)
        vb = *(const float4*)(visA + (size_t)vrow * D_ + k0 + col);
      ushort4 h, l;
      h.x = f2bf(vb.x); l.x = f2bf(vb.x - bf2f(h.x));
      h.y = f2bf(vb.y); l.y = f2bf(vb.y - bf2f(h.y));
      h.z = f2bf(vb.z); l.z = f2bf(vb.z - bf2f(h.z));
      h.w = f2bf(vb.w); l.w = f2bf(vb.w - bf2f(h.w));
      const int e = swz(row, col);
      *(ushort4*)&Bh[e] = h;
      *(ushort4*)&Bl[e] = l;
    }
    __syncthreads();

    #pragma unroll
    for (int kk = 0; kk < 64; kk += 32) {
      const int fc = kk + qq * 8;   // per-lane k offset within tile
      short8 ah[4], al[4], bh[4], bl[4];
      #pragma unroll
      for (int m = 0; m < 4; m++) {
        const int row = 64 * wr + 16 * m + tx;
        ah[m] = ldfrag(Ah, row, fc);
        al[m] = ldfrag(Al, row, fc);
      }
      #pragma unroll
      for (int n = 0; n < 4; n++) {
        const int row = 64 * wc + 16 * n + tx;
        bh[n] = ldfrag(Bh, row, fc);
        bl[n] = ldfrag(Bl, row, fc);
      }
      #pragma unroll
      for (int m = 0; m < 4; m++)
        #pragma unroll
        for (int n = 0; n < 4; n++) {
          acc[m][n] = __builtin_amdgcn_mfma_f32_16x16x32_bf16(
              ah[m], bh[n], acc[m][n], 0, 0, 0);
          acc[m][n] = __builtin_amdgcn_mfma_f32_16x16x32_bf16(
              ah[m], bl[n], acc[m][n], 0, 0, 0);
          acc[m][n] = __builtin_amdgcn_mfma_f32_16x16x32_bf16(
              al[m], bh[n], acc[m][n], 0, 0, 0);
        }
    }
    __syncthreads();
  }

  // Top-2 epilogue. C/D layout (m89-verified): col = lane&15, row = qq*4 + r.
  // Output row (b) = 64*wr + 16*m + 4*qq + r; col (v) = v0 + 64*wc + 16*n + tx.
  #pragma unroll
  for (int m = 0; m < 4; m++)
    #pragma unroll
    for (int r = 0; r < 4; r++) {
      float v1 = -INFINITY, v2 = -INFINITY;
      int i1 = 0x7fffffff;
      #pragma unroll
      for (int n = 0; n < 4; n++) {
        const int vv = v0 + 64 * wc + 16 * n + tx;
        const float x = acc[m][n][r];
        if (vv < V_) {
          if (x > v1) { v2 = v1; v1 = x; i1 = vv; }
          else if (x > v2) { v2 = x; }
        }
      }
      #pragma unroll
      for (int off = 8; off >= 1; off >>= 1) {
        const float ov1 = __shfl_xor(v1, off, 16);
        const float ov2 = __shfl_xor(v2, off, 16);
        const int   oi1 = __shfl_xor(i1, off, 16);
        if (ov1 > v1 || (ov1 == v1 && oi1 < i1)) {
          v2 = fmaxf(v1, ov2); v1 = ov1; i1 = oi1;
        } else {
          v2 = fmaxf(v2, ov1);
        }
      }
      if (tx == 0) {
        const int row = 64 * wr + 16 * m + 4 * qq + r;
        p1buf[wc][row] = v1; p2buf[wc][row] = v2; i1buf[wc][row] = i1;
      }
    }
  __syncthreads();

  // Merge the two column-halves (wc=0 has smaller v: tie keeps smaller index).
  if (t < 128) {
    float v1 = p1buf[0][t], v2 = p2buf[0][t];
    int i1 = i1buf[0][t];
    const float ov1 = p1buf[1][t], ov2 = p2buf[1][t];
    const int oi1 = i1buf[1][t];
    if (ov1 > v1) { v2 = fmaxf(v1, ov2); v1 = ov1; i1 = oi1; }
    else          { v2 = fmaxf(v2, ov1); }
    const int mrow = c * B_ + t;
    const size_t o = ((size_t)mrow * B_ + a) * NCH + nch;
    pv1[o] = v1; pv2[o] = v2; pi1[o] = i1;
  }
}

// ---------------------------------------------------------------------------
// Kernel 2: merge the 7 chunk-partials -> max0[m][a], max1[m][a], diag idx.
// ---------------------------------------------------------------------------
__global__ void reduce_top2(const float* __restrict__ pv1,
                            const float* __restrict__ pv2,
                            const int* __restrict__ pi1,
                            float* __restrict__ max0, float* __restrict__ max1,
                            int* __restrict__ didx) {
  const int idx = blockIdx.x * 256 + threadIdx.x;  // m*128 + a
  if (idx >= M_ * B_) return;
  float v1 = -INFINITY, v2 = -INFINITY;
  int i1 = 0x7fffffff;
  #pragma unroll
  for (int nc = 0; nc < NCH; nc++) {
    const size_t o = (size_t)idx * NCH + nc;
    const float ov1 = pv1[o], ov2 = pv2[o];
    const int oi1 = pi1[o];
    if (ov1 > v1 || (ov1 == v1 && oi1 < i1)) {
      v2 = fmaxf(v1, ov2); v1 = ov1; i1 = oi1;
    } else {
      v2 = fmaxf(v2, ov1);
    }
  }
  max0[idx] = v1;
  max1[idx] = v2;
  const int m = idx >> 7, a = idx & 127;
  const int b = m & 127, cc = m >> 7;
  if (b == a) didx[(cc << 7) + b] = i1;
}

// ---------------------------------------------------------------------------
// Kernel 3a: gather selected[c][b][:] = vis[b, diag_idx[c][b], :]
// ---------------------------------------------------------------------------
__global__ void gather_sel(const float* __restrict__ vis,
                           const int* __restrict__ didx,
                           float* __restrict__ sel) {
  const int cb = blockIdx.x;           // c*128 + b
  const int b = cb & 127;
  const int v = didx[cb];
  const float4* src = (const float4*)(vis + ((size_t)b * V_ + v) * D_);
  float4* dst = (float4*)(sel + (size_t)cb * D_);
  dst[threadIdx.x] = src[threadIdx.x]; // 128 threads x float4 = 512 floats
}

// ---------------------------------------------------------------------------
// Kernel 3b: three small 128x128 (K=512) NT GEMMs per case (L2-resident).
// g=0: lan_adj ; g=1: img_adj ; g=2: logits. 4-row register blocking: each
// thread computes O[i0..i0+3][j] sharing the y row load across 4 outputs.
// ---------------------------------------------------------------------------
__global__ __launch_bounds__(256)
void small_gemms(const float* __restrict__ lan, const float* __restrict__ sel,
                 float* __restrict__ lan_adj, float* __restrict__ img_adj,
                 float* __restrict__ logits) {
  const int c = blockIdx.z, g = blockIdx.y;
  const int t = threadIdx.x;
  const int j = t & 127;
  const int i0 = blockIdx.x * 8 + (t >> 7) * 4;   // grid.x = 16
  const float4* xp[4];
  const float4* yp;
  float* O;
  #pragma unroll
  for (int r = 0; r < 4; r++) {
    const int i = i0 + r;
    xp[r] = (g == 0) ? (const float4*)(lan + (size_t)(i * 3 + c) * D_)
                     : (const float4*)(sel + ((size_t)c * B_ + i) * D_);
  }
  if (g == 2) yp = (const float4*)(lan + (size_t)(j * 3 + c) * D_);
  else if (g == 0) yp = (const float4*)(lan + (size_t)(j * 3 + c) * D_);
  else yp = (const float4*)(sel + ((size_t)c * B_ + j) * D_);
  O = (g == 0) ? lan_adj : (g == 1) ? img_adj : logits;

  float s[4] = {0.f, 0.f, 0.f, 0.f};
  #pragma unroll 4
  for (int k = 0; k < D_ / 4; k++) {
    const float4 y = yp[k];
    #pragma unroll
    for (int r = 0; r < 4; r++) {
      const float4 x = xp[r][k];
      s[r] += x.x * y.x + x.y * y.y + x.z * y.z + x.w * y.w;
    }
  }
  #pragma unroll
  for (int r = 0; r < 4; r++)
    O[(size_t)c * (B_ * B_) + (size_t)(i0 + r) * B_ + j] = s[r];
}

// ---------------------------------------------------------------------------
// Reductions (128-thread block = 2 waves)
// ---------------------------------------------------------------------------
__device__ __forceinline__ float wsum(float v) {
  #pragma unroll
  for (int m = 32; m >= 1; m >>= 1) v += __shfl_xor(v, m);
  return v;
}
__device__ __forceinline__ float wmax(float v) {
  #pragma unroll
  for (int m = 32; m >= 1; m >>= 1) v = fmaxf(v, __shfl_xor(v, m));
  return v;
}
__device__ __forceinline__ float bsum(float v, float* sb) {
  v = wsum(v);
  __syncthreads();
  if ((threadIdx.x & 63) == 0) sb[threadIdx.x >> 6] = v;
  __syncthreads();
  return sb[0] + sb[1];
}
__device__ __forceinline__ float bmax(float v, float* sb) {
  v = wmax(v);
  __syncthreads();
  if ((threadIdx.x & 63) == 0) sb[threadIdx.x >> 6] = v;
  __syncthreads();
  return fmaxf(sb[0], sb[1]);
}

// ---------------------------------------------------------------------------
// Kernel 4: per (c, row i): CE term, score row (softmax of max0), loss_fns row.
// acc layout: [0..2]=ce_sum, [3..5]=fns_sum, [6..8]=t1_sum, [9..11]=t2_sum
// ---------------------------------------------------------------------------
__global__ __launch_bounds__(128)
void row_losses(const float* __restrict__ max0, const float* __restrict__ max1,
                const float* __restrict__ lan_adj, const float* __restrict__ img_adj,
                const float* __restrict__ logits, float* __restrict__ score,
                float* __restrict__ acc) {
  __shared__ float sb[2];
  const int c = blockIdx.y, i = blockIdx.x, j = threadIdx.x;
  const size_t row = ((size_t)c * B_ + i) * B_;
  const float m0 = max0[row + j];
  const float m1 = (j == i) ? -INFINITY : max1[row + j];

  // CE over 255-vector [max0 row (128) ; max1 row minus col i (127)]
  const float rmax = bmax(fmaxf(m0, m1), sb);
  const float se = bsum(expf(m0 - rmax) + ((j == i) ? 0.f : expf(m1 - rmax)), sb);
  if (j == 0) {
    const float lse = logf(se) + rmax;
    atomicAdd(&acc[c], lse - max0[row + i]);  // -log_softmax at diag
  }

  // score = row softmax of max0
  const float smax = bmax(m0, sb);
  const float e0 = expf(m0 - smax);
  const float ssum = bsum(e0, sb);
  score[row + j] = e0 / ssum;

  // loss_fns row: |softmax((img+lan)/2) - softmax(logits)|
  const float u = 0.5f * (lan_adj[row + j] + img_adj[row + j]);
  const float gg = logits[row + j];
  const float umax = bmax(u, sb);
  const float eu = expf(u - umax);
  const float usum = bsum(eu, sb);
  const float gmax = bmax(gg, sb);
  const float eg = expf(gg - gmax);
  const float gsum = bsum(eg, sb);
  const float dsum = bsum(fabsf(eu / usum - eg / gsum), sb);
  if (j == 0) atomicAdd(&acc[3 + c], dsum);
}

// ---------------------------------------------------------------------------
// Kernel 5: pair regularization sums over off-diagonal (i, j).
// ---------------------------------------------------------------------------
__global__ __launch_bounds__(256)
void pair_kernel(const float* __restrict__ score, float* __restrict__ acc) {
  const int c = blockIdx.y;
  const int idx = blockIdx.x * 256 + threadIdx.x;  // 0..16383
  const int i = idx >> 7, j = idx & 127;
  const float* S = score + (size_t)c * (B_ * B_);
  float t1 = 0.f, t2 = 0.f;
  if (i != j) {
    const float dii = S[i * B_ + i], djj = S[j * B_ + j];
    const float sij = S[i * B_ + j], sji = S[j * B_ + i];
    t1 = fabsf(dii - sji - djj + sij);
    t2 = fabsf(dii - sij - djj + sji);
  }
  t1 = wsum(t1);
  t2 = wsum(t2);
  if ((threadIdx.x & 63) == 0) {
    atomicAdd(&acc[6 + c], t1);
    atomicAdd(&acc[9 + c], t2);
  }
}

// ---------------------------------------------------------------------------
// Kernel 6: assemble the scalar loss.
// ---------------------------------------------------------------------------
__global__ void finalize(const float* __restrict__ acc, float* __restrict__ out) {
  if (threadIdx.x == 0 && blockIdx.x == 0) {
    float total = 0.f;
    const float denom = (float)(B_ * (B_ - 1));
    for (int c = 0; c < 3; c++) {
      const float ce  = acc[c] / (float)B_;
      const float fns = acc[3 + c] / (float)(B_ * B_);
      const float p1  = acc[6 + c] / denom;
      const float p2  = acc[9 + c] / denom;
      total += ce + 0.1f * fns + 0.1f * (fmaxf(p1, 0.f) + fmaxf(p2, 0.f));
    }
    out[0] = total / 3.f;
  }
}

__global__ void zero_acc(float* __restrict__ acc) {
  if (threadIdx.x < 12) acc[threadIdx.x] = 0.f;
}

// ---------------------------------------------------------------------------
extern "C" void kernel_launch(void* const* d_in, const int* in_sizes, int n_in,
                              void* d_out, int out_size, void* d_ws, size_t ws_size,
                              hipStream_t stream) {
  const float* vis = (const float*)d_in[0];  // [128][784][512]
  const float* lan = (const float*)d_in[1];  // [128][3][512]
  float* out = (float*)d_out;

  // Workspace layout (float-equivalents). Total ~= 6.9 MB.
  float* w = (float*)d_ws;
  float* pv1 = w;                         // [384][128][7]
  float* pv2 = pv1 + (size_t)M_ * B_ * NCH;
  int*   pi1 = (int*)(pv2 + (size_t)M_ * B_ * NCH);
  float* max0 = (float*)(pi1 + (size_t)M_ * B_ * NCH);  // [3][128][128]
  float* max1 = max0 + 3 * B_ * B_;
  int*   didx = (int*)(max1 + 3 * B_ * B_);             // [3][128]
  float* sel = (float*)(didx + 3 * B_);                 // [3][128][512]
  float* lan_adj = sel + (size_t)3 * B_ * D_;
  float* img_adj = lan_adj + 3 * B_ * B_;
  float* logits  = img_adj + 3 * B_ * B_;
  float* score   = logits + 3 * B_ * B_;
  float* acc     = score + 3 * B_ * B_;                 // 12 floats
  ushort* lanbf  = (ushort*)(acc + 16);                 // 3*8*2*8192 ushorts

  zero_acc<<<dim3(1), dim3(32), 0, stream>>>(acc);
  prep_lan<<<dim3(3, 8), dim3(256), 0, stream>>>(lan, lanbf);
  gemm_top2<<<dim3(NBLK), dim3(256), 0, stream>>>(vis, lanbf, pv1, pv2, pi1);
  reduce_top2<<<dim3((M_ * B_ + 255) / 256), dim3(256), 0, stream>>>(
      pv1, pv2, pi1, max0, max1, didx);
  gather_sel<<<dim3(3 * B_), dim3(128), 0, stream>>>(vis, didx, sel);
  small_gemms<<<dim3(16, 3, 3), dim3(256), 0, stream>>>(
      lan, sel, lan_adj, img_adj, logits);
  row_losses<<<dim3(B_, 3), dim3(128), 0, stream>>>(
      max0, max1, lan_adj, img_adj, logits, score, acc);
  pair_kernel<<<dim3(B_ * B_ / 256, 3), dim3(256), 0, stream>>>(score, acc);
  finalize<<<dim3(1), dim3(1), 0, stream>>>(acc, out);
}

// Round 4
// 599.297 us; speedup vs baseline: 1.0791x; 1.0791x over previous
//
#include <hip/hip_runtime.h>
#include <math.h>

// Problem constants (B=128, V=784, D=512, 3 cases)
#define B_   128
#define V_   784
#define D_   512
#define M_   384      // 3*B rows (case-major: m = c*128 + b)
#define NCH  7        // ceil(784/128) column chunks
#define LO_OFF 196608 // lanbf: lo-half offset in ushorts (3*128*512)

typedef __attribute__((ext_vector_type(8))) short short8;   // 8 bf16 (4 VGPRs)
typedef __attribute__((ext_vector_type(4))) float f32x4;    // MFMA accumulator

// fp32 -> bf16 round-to-nearest-even (finite inputs)
__device__ __forceinline__ ushort f2bf(float x) {
  uint u = __float_as_uint(x);
  u += 0x7fff + ((u >> 16) & 1);
  return (ushort)(u >> 16);
}
__device__ __forceinline__ float bf2f(ushort h) {
  return __uint_as_float((uint)h << 16);
}

// Swizzled element index into a [128][64] ushort LDS tile.
// elem ^= ((row&7)<<3)  (byte ^= (row&7)<<4): preserves 8/16B chunks, spreads
// the 128B row stride across 8 16B slots -> conflict-free ds_read_b128
// (measured 0 conflicts in round 3).
__device__ __forceinline__ int swz(int row, int col) {
  return (row * 64 + col) ^ ((row & 7) << 3);
}

__device__ __forceinline__ short8 ldfrag(const ushort* base, int row, int col) {
  union { uint4 u; short8 s; } t;
  t.u = *(const uint4*)(base + swz(row, col));
  return t.s;
}

// ---------------------------------------------------------------------------
// Kernel 0: precompute lan hi/lo bf16 in FRAGMENT order so the GEMM waves can
// read A directly from global (L2-hot, 786 KB total), no LDS staging:
//   chunk16B[ ((((c*8+kb)*2+kk)*8 + m16)*64 + lane) ] = A[16*m16 + (lane&15)]
//                                  [kb*64 + kk*32 + (lane>>4)*8 ... +8)
// hi at [0, 24576) chunks, lo at [24576, 49152).
// ---------------------------------------------------------------------------
__global__ __launch_bounds__(256)
void prep_lan(const float* __restrict__ lan, ushort* __restrict__ lanbf,
              float* __restrict__ acc) {
  const int c = blockIdx.x, kb = blockIdx.y, t = threadIdx.x;
  if (c == 0 && kb == 0 && t < 12) acc[t] = 0.f;   // fused zero_acc
  #pragma unroll
  for (int i = 0; i < 4; i++) {
    const int u = t + 256 * i;          // 0..1023 = kk*512 + m16*64 + lane
    const int kk = u >> 9;
    const int m16 = (u >> 6) & 7;
    const int lane = u & 63;
    const int row = m16 * 16 + (lane & 15);
    const int k0 = kb * 64 + kk * 32 + (lane >> 4) * 8;
    const float4 v0 = *(const float4*)(lan + (size_t)(row * 3 + c) * D_ + k0);
    const float4 v1 = *(const float4*)(lan + (size_t)(row * 3 + c) * D_ + k0 + 4);
    union { ushort s[8]; uint4 u4; } h, l;
    const float vv[8] = {v0.x, v0.y, v0.z, v0.w, v1.x, v1.y, v1.z, v1.w};
    #pragma unroll
    for (int e = 0; e < 8; e++) {
      h.s[e] = f2bf(vv[e]);
      l.s[e] = f2bf(vv[e] - bf2f(h.s[e]));
    }
    const size_t ch = ((((size_t)(c * 8 + kb) * 2 + kk) * 8 + m16) * 64 + lane);
    *(uint4*)&lanbf[ch * 8] = h.u4;
    *(uint4*)&lanbf[LO_OFF + ch * 8] = l.u4;
  }
}

// ---------------------------------------------------------------------------
// Kernel 1: sim GEMM, 3-case fused, fused top-2.
// Block = (a, nch): S_c[b, v] = lan_c[b].vis[a, v] for c=0..2; tile 128x128,
// BK=64, K=512. 512 threads = 8 waves; wave (wr,wc) owns rows [64wr,64wr+64)
// x cols [32wc, 32wc+32) for every case. S = Ah*Bh + Ah*Bl + Al*Bh.
// vis tile staged ONCE (not 3x): regs -> convert -> double-buffered LDS,
// next-kb loads issued before current-kb compute (1 barrier per kb).
// A-fragments read directly from fragment-ordered global lanbf (L2-hot).
// ---------------------------------------------------------------------------
__global__ __launch_bounds__(512)
void gemm_top2(const float* __restrict__ vis, const ushort* __restrict__ lanbf,
               float* __restrict__ pv1, float* __restrict__ pv2,
               int* __restrict__ pi1) {
  const int id = blockIdx.x;     // 0..895
  const int a = id / NCH;
  const int nch = id - NCH * a;

  const int t = threadIdx.x;
  const int lane = t & 63, wid = t >> 6;
  const int tx = lane & 15, qq = lane >> 4;
  const int wr = wid >> 2, wc = wid & 3;

  // [buf][ hi 8192 | lo 8192 ] swizzled [128][64] ushort tiles (64 KB)
  __shared__ __align__(16) ushort Bsm[2][16384];

  f32x4 acc[3][4][2];
  const f32x4 zz = {0.f, 0.f, 0.f, 0.f};
  #pragma unroll
  for (int c = 0; c < 3; c++)
    #pragma unroll
    for (int m = 0; m < 4; m++)
      #pragma unroll
      for (int n = 0; n < 2; n++) acc[c][m][n] = zz;

  const int v0 = nch * 128;
  const float* visA = vis + (size_t)a * V_ * D_;

  float4 breg[4];
  // prologue: load kb=0, convert into buf 0
  #pragma unroll
  for (int i = 0; i < 4; i++) {
    const int f = t + 512 * i;
    const int row = f >> 4, col = (f & 15) * 4;
    const int vrow = v0 + row;
    breg[i] = (vrow < V_)
        ? *(const float4*)(visA + (size_t)vrow * D_ + col)
        : make_float4(0.f, 0.f, 0.f, 0.f);
  }
  #pragma unroll
  for (int i = 0; i < 4; i++) {
    const int f = t + 512 * i;
    const int row = f >> 4, col = (f & 15) * 4;
    const float4 v = breg[i];
    ushort4 h, l;
    h.x = f2bf(v.x); l.x = f2bf(v.x - bf2f(h.x));
    h.y = f2bf(v.y); l.y = f2bf(v.y - bf2f(h.y));
    h.z = f2bf(v.z); l.z = f2bf(v.z - bf2f(h.z));
    h.w = f2bf(v.w); l.w = f2bf(v.w - bf2f(h.w));
    const int e = swz(row, col);
    *(ushort4*)&Bsm[0][e] = h;
    *(ushort4*)&Bsm[0][8192 + e] = l;
  }
  __syncthreads();

  for (int kb = 0; kb < 8; kb++) {
    const int cur = kb & 1;
    // issue next-kb global loads early (hide HBM latency under MFMAs)
    if (kb < 7) {
      #pragma unroll
      for (int i = 0; i < 4; i++) {
        const int f = t + 512 * i;
        const int row = f >> 4, col = (f & 15) * 4;
        const int vrow = v0 + row;
        breg[i] = (vrow < V_)
            ? *(const float4*)(visA + (size_t)vrow * D_ + (kb + 1) * 64 + col)
            : make_float4(0.f, 0.f, 0.f, 0.f);
      }
    }
    // compute current kb from Bsm[cur] + global A-fragments
    const ushort* Bcur = &Bsm[cur][0];
    #pragma unroll
    for (int kk = 0; kk < 2; kk++) {
      short8 bh[2], bl[2];
      #pragma unroll
      for (int n = 0; n < 2; n++) {
        const int brow = 32 * wc + 16 * n + tx;
        const int bcol = kk * 32 + qq * 8;
        bh[n] = ldfrag(Bcur, brow, bcol);
        bl[n] = ldfrag(Bcur + 8192, brow, bcol);
      }
      #pragma unroll
      for (int c = 0; c < 3; c++) {
        const size_t ch0 =
            (((size_t)(c * 8 + kb) * 2 + kk) * 8 + wr * 4) * 64 + lane;
        short8 ah[4], al[4];
        #pragma unroll
        for (int m = 0; m < 4; m++) {
          ah[m] = *(const short8*)(lanbf + (ch0 + m * 64) * 8);
          al[m] = *(const short8*)(lanbf + (size_t)LO_OFF + (ch0 + m * 64) * 8);
        }
        #pragma unroll
        for (int m = 0; m < 4; m++)
          #pragma unroll
          for (int n = 0; n < 2; n++) {
            acc[c][m][n] = __builtin_amdgcn_mfma_f32_16x16x32_bf16(
                ah[m], bh[n], acc[c][m][n], 0, 0, 0);
            acc[c][m][n] = __builtin_amdgcn_mfma_f32_16x16x32_bf16(
                ah[m], bl[n], acc[c][m][n], 0, 0, 0);
            acc[c][m][n] = __builtin_amdgcn_mfma_f32_16x16x32_bf16(
                al[m], bh[n], acc[c][m][n], 0, 0, 0);
          }
      }
    }
    // convert + store next tile into the other buffer; ONE barrier per kb
    if (kb < 7) {
      #pragma unroll
      for (int i = 0; i < 4; i++) {
        const int f = t + 512 * i;
        const int row = f >> 4, col = (f & 15) * 4;
        const float4 v = breg[i];
        ushort4 h, l;
        h.x = f2bf(v.x); l.x = f2bf(v.x - bf2f(h.x));
        h.y = f2bf(v.y); l.y = f2bf(v.y - bf2f(h.y));
        h.z = f2bf(v.z); l.z = f2bf(v.z - bf2f(h.z));
        h.w = f2bf(v.w); l.w = f2bf(v.w - bf2f(h.w));
        const int e = swz(row, col);
        *(ushort4*)&Bsm[cur ^ 1][e] = h;
        *(ushort4*)&Bsm[cur ^ 1][8192 + e] = l;
      }
    }
    __syncthreads();
  }

  // Epilogue: per-case top-2. C/D layout: col=tx, row=4*qq+r within 16x16.
  // Global row = 64wr+16m+4qq+r; col(v) = v0 + 32wc + 16n + tx.
  float* p1b = (float*)&Bsm[0][0];      // [4][128] (reuse LDS)
  float* p2b = p1b + 512;
  int*   i1b = (int*)(p2b + 512);
  #pragma unroll
  for (int c = 0; c < 3; c++) {
    #pragma unroll
    for (int m = 0; m < 4; m++)
      #pragma unroll
      for (int r = 0; r < 4; r++) {
        float v1 = -INFINITY, v2 = -INFINITY;
        int i1 = 0x7fffffff;
        #pragma unroll
        for (int n = 0; n < 2; n++) {
          const int vv = v0 + 32 * wc + 16 * n + tx;
          const float x = acc[c][m][n][r];
          if (vv < V_) {
            if (x > v1) { v2 = v1; v1 = x; i1 = vv; }
            else if (x > v2) { v2 = x; }
          }
        }
        #pragma unroll
        for (int off = 8; off >= 1; off >>= 1) {
          const float ov1 = __shfl_xor(v1, off, 16);
          const float ov2 = __shfl_xor(v2, off, 16);
          const int   oi1 = __shfl_xor(i1, off, 16);
          if (ov1 > v1 || (ov1 == v1 && oi1 < i1)) {
            v2 = fmaxf(v1, ov2); v1 = ov1; i1 = oi1;
          } else {
            v2 = fmaxf(v2, ov1);
          }
        }
        if (tx == 0) {
          const int grow = 64 * wr + 16 * m + 4 * qq + r;
          p1b[wc * 128 + grow] = v1;
          p2b[wc * 128 + grow] = v2;
          i1b[wc * 128 + grow] = i1;
        }
      }
    __syncthreads();
    if (t < 128) {
      float v1 = p1b[t], v2 = p2b[t];
      int i1 = i1b[t];
      #pragma unroll
      for (int w = 1; w < 4; w++) {    // ascending v: tie keeps smaller index
        const float ov1 = p1b[w * 128 + t], ov2 = p2b[w * 128 + t];
        const int oi1 = i1b[w * 128 + t];
        if (ov1 > v1) { v2 = fmaxf(v1, ov2); v1 = ov1; i1 = oi1; }
        else          { v2 = fmaxf(v2, ov1); }
      }
      // coalesced [a][nch][m] layout: 1.5 KB contiguous per (block, case)
      const size_t o = ((size_t)a * NCH + nch) * M_ + c * B_ + t;
      pv1[o] = v1; pv2[o] = v2; pi1[o] = i1;
    }
    __syncthreads();
  }
}

// ---------------------------------------------------------------------------
// Kernel 2: merge the 7 chunk-partials -> max0[m][a], max1[m][a], diag idx.
// pv layout is [a][nch][m].
// ---------------------------------------------------------------------------
__global__ void reduce_top2(const float* __restrict__ pv1,
                            const float* __restrict__ pv2,
                            const int* __restrict__ pi1,
                            float* __restrict__ max0, float* __restrict__ max1,
                            int* __restrict__ didx) {
  const int idx = blockIdx.x * 256 + threadIdx.x;  // m*128 + a
  if (idx >= M_ * B_) return;
  const int m = idx >> 7, a = idx & 127;
  float v1 = -INFINITY, v2 = -INFINITY;
  int i1 = 0x7fffffff;
  #pragma unroll
  for (int nc = 0; nc < NCH; nc++) {
    const size_t o = ((size_t)a * NCH + nc) * M_ + m;
    const float ov1 = pv1[o], ov2 = pv2[o];
    const int oi1 = pi1[o];
    if (ov1 > v1 || (ov1 == v1 && oi1 < i1)) {
      v2 = fmaxf(v1, ov2); v1 = ov1; i1 = oi1;
    } else {
      v2 = fmaxf(v2, ov1);
    }
  }
  max0[idx] = v1;
  max1[idx] = v2;
  const int b = m & 127, cc = m >> 7;
  if (b == a) didx[(cc << 7) + b] = i1;
}

// ---------------------------------------------------------------------------
// Kernel 3a: gather selected[c][b][:] = vis[b, diag_idx[c][b], :]
// ---------------------------------------------------------------------------
__global__ void gather_sel(const float* __restrict__ vis,
                           const int* __restrict__ didx,
                           float* __restrict__ sel) {
  const int cb = blockIdx.x;           // c*128 + b
  const int b = cb & 127;
  const int v = didx[cb];
  const float4* src = (const float4*)(vis + ((size_t)b * V_ + v) * D_);
  float4* dst = (float4*)(sel + (size_t)cb * D_);
  dst[threadIdx.x] = src[threadIdx.x]; // 128 threads x float4 = 512 floats
}

// ---------------------------------------------------------------------------
// Kernel 3b: three small 128x128 (K=512) NT GEMMs per case (L2-resident).
// g=0: lan_adj ; g=1: img_adj ; g=2: logits. 4-row register blocking.
// ---------------------------------------------------------------------------
__global__ __launch_bounds__(256)
void small_gemms(const float* __restrict__ lan, const float* __restrict__ sel,
                 float* __restrict__ lan_adj, float* __restrict__ img_adj,
                 float* __restrict__ logits) {
  const int c = blockIdx.z, g = blockIdx.y;
  const int t = threadIdx.x;
  const int j = t & 127;
  const int i0 = blockIdx.x * 8 + (t >> 7) * 4;   // grid.x = 16
  const float4* xp[4];
  const float4* yp;
  float* O;
  #pragma unroll
  for (int r = 0; r < 4; r++) {
    const int i = i0 + r;
    xp[r] = (g == 0) ? (const float4*)(lan + (size_t)(i * 3 + c) * D_)
                     : (const float4*)(sel + ((size_t)c * B_ + i) * D_);
  }
  if (g == 1) yp = (const float4*)(sel + ((size_t)c * B_ + j) * D_);
  else yp = (const float4*)(lan + (size_t)(j * 3 + c) * D_);
  O = (g == 0) ? lan_adj : (g == 1) ? img_adj : logits;

  float s[4] = {0.f, 0.f, 0.f, 0.f};
  #pragma unroll 4
  for (int k = 0; k < D_ / 4; k++) {
    const float4 y = yp[k];
    #pragma unroll
    for (int r = 0; r < 4; r++) {
      const float4 x = xp[r][k];
      s[r] += x.x * y.x + x.y * y.y + x.z * y.z + x.w * y.w;
    }
  }
  #pragma unroll
  for (int r = 0; r < 4; r++)
    O[(size_t)c * (B_ * B_) + (size_t)(i0 + r) * B_ + j] = s[r];
}

// ---------------------------------------------------------------------------
// Reductions (128-thread block = 2 waves)
// ---------------------------------------------------------------------------
__device__ __forceinline__ float wsum(float v) {
  #pragma unroll
  for (int m = 32; m >= 1; m >>= 1) v += __shfl_xor(v, m);
  return v;
}
__device__ __forceinline__ float wmax(float v) {
  #pragma unroll
  for (int m = 32; m >= 1; m >>= 1) v = fmaxf(v, __shfl_xor(v, m));
  return v;
}
__device__ __forceinline__ float bsum(float v, float* sb) {
  v = wsum(v);
  __syncthreads();
  if ((threadIdx.x & 63) == 0) sb[threadIdx.x >> 6] = v;
  __syncthreads();
  return sb[0] + sb[1];
}
__device__ __forceinline__ float bmax(float v, float* sb) {
  v = wmax(v);
  __syncthreads();
  if ((threadIdx.x & 63) == 0) sb[threadIdx.x >> 6] = v;
  __syncthreads();
  return fmaxf(sb[0], sb[1]);
}

// ---------------------------------------------------------------------------
// Kernel 4: per (c, row i): CE term, score row (softmax of max0), loss_fns row.
// acc layout: [0..2]=ce_sum, [3..5]=fns_sum, [6..8]=t1_sum, [9..11]=t2_sum
// ---------------------------------------------------------------------------
__global__ __launch_bounds__(128)
void row_losses(const float* __restrict__ max0, const float* __restrict__ max1,
                const float* __restrict__ lan_adj, const float* __restrict__ img_adj,
                const float* __restrict__ logits, float* __restrict__ score,
                float* __restrict__ acc) {
  __shared__ float sb[2];
  const int c = blockIdx.y, i = blockIdx.x, j = threadIdx.x;
  const size_t row = ((size_t)c * B_ + i) * B_;
  const float m0 = max0[row + j];
  const float m1 = (j == i) ? -INFINITY : max1[row + j];

  // CE over 255-vector [max0 row (128) ; max1 row minus col i (127)]
  const float rmax = bmax(fmaxf(m0, m1), sb);
  const float se = bsum(expf(m0 - rmax) + ((j == i) ? 0.f : expf(m1 - rmax)), sb);
  if (j == 0) {
    const float lse = logf(se) + rmax;
    atomicAdd(&acc[c], lse - max0[row + i]);  // -log_softmax at diag
  }

  // score = row softmax of max0
  const float smax = bmax(m0, sb);
  const float e0 = expf(m0 - smax);
  const float ssum = bsum(e0, sb);
  score[row + j] = e0 / ssum;

  // loss_fns row: |softmax((img+lan)/2) - softmax(logits)|
  const float u = 0.5f * (lan_adj[row + j] + img_adj[row + j]);
  const float gg = logits[row + j];
  const float umax = bmax(u, sb);
  const float eu = expf(u - umax);
  const float usum = bsum(eu, sb);
  const float gmax = bmax(gg, sb);
  const float eg = expf(gg - gmax);
  const float gsum = bsum(eg, sb);
  const float dsum = bsum(fabsf(eu / usum - eg / gsum), sb);
  if (j == 0) atomicAdd(&acc[3 + c], dsum);
}

// ---------------------------------------------------------------------------
// Kernel 5: pair regularization sums over off-diagonal (i, j).
// ---------------------------------------------------------------------------
__global__ __launch_bounds__(256)
void pair_kernel(const float* __restrict__ score, float* __restrict__ acc) {
  const int c = blockIdx.y;
  const int idx = blockIdx.x * 256 + threadIdx.x;  // 0..16383
  const int i = idx >> 7, j = idx & 127;
  const float* S = score + (size_t)c * (B_ * B_);
  float t1 = 0.f, t2 = 0.f;
  if (i != j) {
    const float dii = S[i * B_ + i], djj = S[j * B_ + j];
    const float sij = S[i * B_ + j], sji = S[j * B_ + i];
    t1 = fabsf(dii - sji - djj + sij);
    t2 = fabsf(dii - sij - djj + sji);
  }
  t1 = wsum(t1);
  t2 = wsum(t2);
  if ((threadIdx.x & 63) == 0) {
    atomicAdd(&acc[6 + c], t1);
    atomicAdd(&acc[9 + c], t2);
  }
}

// ---------------------------------------------------------------------------
// Kernel 6: assemble the scalar loss.
// ---------------------------------------------------------------------------
__global__ void finalize(const float* __restrict__ acc, float* __restrict__ out) {
  if (threadIdx.x == 0 && blockIdx.x == 0) {
    float total = 0.f;
    const float denom = (float)(B_ * (B_ - 1));
    for (int c = 0; c < 3; c++) {
      const float ce  = acc[c] / (float)B_;
      const float fns = acc[3 + c] / (float)(B_ * B_);
      const float p1  = acc[6 + c] / denom;
      const float p2  = acc[9 + c] / denom;
      total += ce + 0.1f * fns + 0.1f * (fmaxf(p1, 0.f) + fmaxf(p2, 0.f));
    }
    out[0] = total / 3.f;
  }
}

// ---------------------------------------------------------------------------
extern "C" void kernel_launch(void* const* d_in, const int* in_sizes, int n_in,
                              void* d_out, int out_size, void* d_ws, size_t ws_size,
                              hipStream_t stream) {
  const float* vis = (const float*)d_in[0];  // [128][784][512]
  const float* lan = (const float*)d_in[1];  // [128][3][512]
  float* out = (float*)d_out;

  // Workspace layout (float-equivalents). Total ~= 6.9 MB.
  float* w = (float*)d_ws;
  float* pv1 = w;                         // [128 a][7 nch][384 m]
  float* pv2 = pv1 + (size_t)M_ * B_ * NCH;
  int*   pi1 = (int*)(pv2 + (size_t)M_ * B_ * NCH);
  float* max0 = (float*)(pi1 + (size_t)M_ * B_ * NCH);  // [3][128][128]
  float* max1 = max0 + 3 * B_ * B_;
  int*   didx = (int*)(max1 + 3 * B_ * B_);             // [3][128]
  float* sel = (float*)(didx + 3 * B_);                 // [3][128][512]
  float* lan_adj = sel + (size_t)3 * B_ * D_;
  float* img_adj = lan_adj + 3 * B_ * B_;
  float* logits  = img_adj + 3 * B_ * B_;
  float* score   = logits + 3 * B_ * B_;
  float* acc     = score + 3 * B_ * B_;                 // 12 floats (+pad)
  ushort* lanbf  = (ushort*)(acc + 16);                 // 2*196608 ushorts

  prep_lan<<<dim3(3, 8), dim3(256), 0, stream>>>(lan, lanbf, acc);
  gemm_top2<<<dim3(B_ * NCH), dim3(512), 0, stream>>>(vis, lanbf, pv1, pv2, pi1);
  reduce_top2<<<dim3((M_ * B_ + 255) / 256), dim3(256), 0, stream>>>(
      pv1, pv2, pi1, max0, max1, didx);
  gather_sel<<<dim3(3 * B_), dim3(128), 0, stream>>>(vis, didx, sel);
  small_gemms<<<dim3(16, 3, 3), dim3(256), 0, stream>>>(
      lan, sel, lan_adj, img_adj, logits);
  row_losses<<<dim3(B_, 3), dim3(128), 0, stream>>>(
      max0, max1, lan_adj, img_adj, logits, score, acc);
  pair_kernel<<<dim3(B_ * B_ / 256, 3), dim3(256), 0, stream>>>(score, acc);
  finalize<<<dim3(1), dim3(1), 0, stream>>>(acc, out);
}

// Round 5
// 532.078 us; speedup vs baseline: 1.2154x; 1.1263x over previous
//
#include <hip/hip_runtime.h>
#include <math.h>

// Problem constants (B=128, V=784, D=512, 3 cases)
#define B_   128
#define V_   784
#define D_   512
#define M_   384      // 3*B rows (case-major: m = c*128 + b)
#define NCH  7        // ceil(784/128) column chunks

typedef __attribute__((ext_vector_type(8))) short short8;   // 8 bf16 (4 VGPRs)
typedef __attribute__((ext_vector_type(4))) float f32x4;    // MFMA accumulator
typedef unsigned int u32t;

// fp32 -> bf16 round-to-nearest-even (finite inputs)
__device__ __forceinline__ ushort f2bf(float x) {
  uint u = __float_as_uint(x);
  u += 0x7fff + ((u >> 16) & 1);
  return (ushort)(u >> 16);
}
__device__ __forceinline__ float bf2f(ushort h) {
  return __uint_as_float((uint)h << 16);
}

// global -> LDS direct (16B/lane, wave-uniform LDS base + lane*16 dest).
// LDS generic ptr -> AS(3) via uintptr truncation (CK/AITER idiom).
__device__ __forceinline__ void stage16(const void* g, void* l) {
  __builtin_amdgcn_global_load_lds(
      (const __attribute__((address_space(1))) u32t*)g,
      (__attribute__((address_space(3))) u32t*)(uintptr_t)l, 16, 0, 0);
}

// ---------------------------------------------------------------------------
// Kernel 0: lan -> bf16 hi/lo in FRAGMENT-LINEAR per-(c,step) 16KB tiles, so
// gemm stages them with global_load_lds and reads conflict-free:
//   ushort off = (((c*16+s)*2 + h)*8 + m16)*512 + lane*8
//   lane=(tx=b%16, qq=k/8): element (b = m16*16+tx, k = s*32 + qq*8 + e)
// Also zeroes the 12 loss accumulators (block 0).
// ---------------------------------------------------------------------------
__global__ __launch_bounds__(256)
void prep_lan(const float* __restrict__ lan, ushort* __restrict__ lanbf,
              float* __restrict__ acc) {
  const int c = blockIdx.x >> 4, s = blockIdx.x & 15, t = threadIdx.x;
  if (blockIdx.x == 0 && t < 12) acc[t] = 0.f;
  #pragma unroll
  for (int it = 0; it < 2; ++it) {
    const int u = t + it * 256;          // 0..511 = m16*64 + lane
    const int m16 = u >> 6, lane = u & 63;
    const int row = m16 * 16 + (lane & 15);
    const int k = s * 32 + (lane >> 4) * 8;
    const float* src = lan + (size_t)(row * 3 + c) * D_ + k;
    const float4 v0 = *(const float4*)src;
    const float4 v1 = *(const float4*)(src + 4);
    union { ushort s[8]; uint4 q; } H, L;
    const float f[8] = {v0.x, v0.y, v0.z, v0.w, v1.x, v1.y, v1.z, v1.w};
    #pragma unroll
    for (int e = 0; e < 8; ++e) {
      const ushort h = f2bf(f[e]);
      H.s[e] = h; L.s[e] = f2bf(f[e] - bf2f(h));
    }
    const size_t base = ((size_t)(c * 16 + s) * 2) * 8 * 512;
    *(uint4*)&lanbf[base + (size_t)m16 * 512 + lane * 8] = H.q;            // h=0
    *(uint4*)&lanbf[base + 4096 + (size_t)m16 * 512 + lane * 8] = L.q;     // h=1
  }
}

// ---------------------------------------------------------------------------
// Kernel 1: sim GEMM, 3-case fused, fused top-2. Block (a, nch), 512 thr,
// 8 waves = (wr 0..3: 32 rows) x (wc 0..1: 64 cols). K-step = 32, 16 steps.
// Per step, 64KB staged via 64 global_load_lds issues (8/wave):
//   groups 0..47  = A bf16 hi/lo (1KB each):  c = G>>4, sub = G&15 (= h*8+m16)
//   issues 48..63 = B fp32 (2KB groups, 2 issues): v16 = (I-48)>>1, hb = (I-48)&1
// B group layout (2KB, [lane l][8 floats]): lane l holds (v'=l&15, k-quarter
// qq=l>>4)'s 8 floats -> reader lane reads its own 32B, converts to hi/lo bf16.
// Schedule (T3 min-2-phase): STAGE(s+1) -> compute(s) -> vmcnt(0) -> raw
// s_barrier (no compiler lgkmcnt/vmcnt drain; ds_read counter decoupled).
// S = Ah*Bh + Ah*Bl + Al*Bh  (fp32-accurate to ~2^-18).
// ---------------------------------------------------------------------------
__global__ __launch_bounds__(512, 2)
void gemm_top2(const float* __restrict__ vis, const ushort* __restrict__ lanbf,
               float* __restrict__ pv1, float* __restrict__ pv2,
               int* __restrict__ pi1) {
  __shared__ __align__(16) char Lds[131072];   // 2 x (48KB A + 16KB B)

  const int id = blockIdx.x;     // 0..895
  const int a = id / NCH;
  const int nch = id - NCH * a;
  const int t = threadIdx.x;
  const int lane = t & 63, wid = t >> 6;
  const int tx = lane & 15, qq = lane >> 4;
  const int wr = wid >> 1, wc = wid & 1;
  const int v0 = nch * 128;
  const char* visA = (const char*)vis + (size_t)a * V_ * D_ * 4;

  // Precompute the wave's 8 stage sources (lane-varying) + per-step strides.
  const char* gb[8];
  int gstep[8], ldso[8];
  #pragma unroll
  for (int gq = 0; gq < 8; ++gq) {
    const int I = wid * 8 + gq;
    ldso[gq] = I * 1024;
    if (I < 48) {            // A from lanbf: +s*16KB per step
      const int c = I >> 4, sub = I & 15;
      gb[gq] = (const char*)lanbf + (size_t)c * 262144 + sub * 1024 + lane * 16;
      gstep[gq] = 16384;
    } else {                 // B from vis: +s*128B per step (k += 32 floats)
      const int v16 = (I - 48) >> 1, hb = (I - 48) & 1;
      const int vp = (lane >> 1) & 15;          // row within 16-row group
      const int q2 = hb * 2 + (lane >> 5);      // k-quarter 0..3
      const int f4 = lane & 1;                  // 16B half of the 32B
      int v = v0 + v16 * 16 + vp;
      if (v > V_ - 1) v = V_ - 1;               // clamp: no OOB; masked later
      gb[gq] = visA + (size_t)v * 2048 + q2 * 32 + f4 * 16;
      gstep[gq] = 128;
    }
  }

  f32x4 acc[3][2][4];
  const f32x4 zz = {0.f, 0.f, 0.f, 0.f};
  #pragma unroll
  for (int c = 0; c < 3; ++c)
    #pragma unroll
    for (int m = 0; m < 2; ++m)
      #pragma unroll
      for (int n = 0; n < 4; ++n) acc[c][m][n] = zz;

  // prologue: stage step 0 into buf 0
  #pragma unroll
  for (int gq = 0; gq < 8; ++gq) stage16(gb[gq], Lds + ldso[gq]);
  asm volatile("s_waitcnt vmcnt(0)" ::: "memory");
  __builtin_amdgcn_s_barrier();
  asm volatile("" ::: "memory");

  for (int s = 0; s < 16; ++s) {
    const int buf = s & 1;
    char* Lb = Lds + buf * 65536;
    if (s < 15) {   // stage s+1 into the other buffer (lands under compute)
      char* Ln = Lds + (buf ^ 1) * 65536;
      #pragma unroll
      for (int gq = 0; gq < 8; ++gq)
        stage16(gb[gq] + (size_t)(s + 1) * gstep[gq], Ln + ldso[gq]);
    }
    // ---- compute step s ----
    short8 bh[4], bl[4];
    #pragma unroll
    for (int n = 0; n < 4; ++n) {
      const char* bp = Lb + 49152 + (wc * 4 + n) * 2048 + lane * 32;
      const float4 x = *(const float4*)bp;
      const float4 y = *(const float4*)(bp + 16);
      union { ushort s[8]; short8 v; } H, L;
      const float f[8] = {x.x, x.y, x.z, x.w, y.x, y.y, y.z, y.w};
      #pragma unroll
      for (int e = 0; e < 8; ++e) {
        const ushort h = f2bf(f[e]);
        H.s[e] = h; L.s[e] = f2bf(f[e] - bf2f(h));
      }
      bh[n] = H.v; bl[n] = L.v;
    }
    #pragma unroll
    for (int c = 0; c < 3; ++c) {
      short8 ah[2], al[2];
      #pragma unroll
      for (int m = 0; m < 2; ++m) {
        const int sub = wr * 2 + m;
        ah[m] = *(const short8*)(Lb + (c * 16 + sub) * 1024 + lane * 16);
        al[m] = *(const short8*)(Lb + (c * 16 + 8 + sub) * 1024 + lane * 16);
      }
      #pragma unroll
      for (int m = 0; m < 2; ++m)
        #pragma unroll
        for (int n = 0; n < 4; ++n) {
          acc[c][m][n] = __builtin_amdgcn_mfma_f32_16x16x32_bf16(
              ah[m], bh[n], acc[c][m][n], 0, 0, 0);
          acc[c][m][n] = __builtin_amdgcn_mfma_f32_16x16x32_bf16(
              ah[m], bl[n], acc[c][m][n], 0, 0, 0);
          acc[c][m][n] = __builtin_amdgcn_mfma_f32_16x16x32_bf16(
              al[m], bh[n], acc[c][m][n], 0, 0, 0);
        }
    }
    // ---- flip ----
    if (s < 15) asm volatile("s_waitcnt vmcnt(0)" ::: "memory");
    __builtin_amdgcn_s_barrier();
    asm volatile("" ::: "memory");
  }

  // Epilogue: per-case top-2. C/D: col = tx, row = qq*4 + r (m89-verified).
  // Global row = wr*32 + m*16 + qq*4 + r; col(v) = v0 + wc*64 + n*16 + tx.
  float* p1b = (float*)Lds;            // [2 wc][128] (buf0 free: step15 = buf1)
  float* p2b = p1b + 256;
  int*   i1b = (int*)(p2b + 256);
  #pragma unroll
  for (int c = 0; c < 3; ++c) {
    #pragma unroll
    for (int m = 0; m < 2; ++m)
      #pragma unroll
      for (int r = 0; r < 4; ++r) {
        float v1 = -INFINITY, v2 = -INFINITY;
        int i1 = 0x7fffffff;
        #pragma unroll
        for (int n = 0; n < 4; ++n) {
          const int vv = v0 + wc * 64 + n * 16 + tx;
          const float x = acc[c][m][n][r];
          if (vv < V_) {
            if (x > v1) { v2 = v1; v1 = x; i1 = vv; }
            else if (x > v2) { v2 = x; }
          }
        }
        #pragma unroll
        for (int off = 8; off >= 1; off >>= 1) {
          const float ov1 = __shfl_xor(v1, off, 16);
          const float ov2 = __shfl_xor(v2, off, 16);
          const int   oi1 = __shfl_xor(i1, off, 16);
          if (ov1 > v1 || (ov1 == v1 && oi1 < i1)) {
            v2 = fmaxf(v1, ov2); v1 = ov1; i1 = oi1;
          } else {
            v2 = fmaxf(v2, ov1);
          }
        }
        if (tx == 0) {
          const int grow = wr * 32 + m * 16 + qq * 4 + r;
          p1b[wc * 128 + grow] = v1;
          p2b[wc * 128 + grow] = v2;
          i1b[wc * 128 + grow] = i1;
        }
      }
    __syncthreads();
    if (t < 128) {   // merge wc halves (wc0 = smaller v: tie keeps smaller idx)
      float v1 = p1b[t], v2 = p2b[t];
      int i1 = i1b[t];
      const float ov1 = p1b[128 + t], ov2 = p2b[128 + t];
      const int oi1 = i1b[128 + t];
      if (ov1 > v1) { v2 = fmaxf(v1, ov2); v1 = ov1; i1 = oi1; }
      else          { v2 = fmaxf(v2, ov1); }
      const size_t o = ((size_t)a * NCH + nch) * M_ + c * B_ + t;
      pv1[o] = v1; pv2[o] = v2; pi1[o] = i1;
    }
    __syncthreads();
  }
}

// ---------------------------------------------------------------------------
// Kernel 2: merge the 7 chunk-partials -> max0[m][a], max1[m][a], diag idx.
// pv layout is [a][nch][m].
// ---------------------------------------------------------------------------
__global__ void reduce_top2(const float* __restrict__ pv1,
                            const float* __restrict__ pv2,
                            const int* __restrict__ pi1,
                            float* __restrict__ max0, float* __restrict__ max1,
                            int* __restrict__ didx) {
  const int idx = blockIdx.x * 256 + threadIdx.x;  // m*128 + a
  if (idx >= M_ * B_) return;
  const int m = idx >> 7, a = idx & 127;
  float v1 = -INFINITY, v2 = -INFINITY;
  int i1 = 0x7fffffff;
  #pragma unroll
  for (int nc = 0; nc < NCH; nc++) {
    const size_t o = ((size_t)a * NCH + nc) * M_ + m;
    const float ov1 = pv1[o], ov2 = pv2[o];
    const int oi1 = pi1[o];
    if (ov1 > v1 || (ov1 == v1 && oi1 < i1)) {
      v2 = fmaxf(v1, ov2); v1 = ov1; i1 = oi1;
    } else {
      v2 = fmaxf(v2, ov1);
    }
  }
  max0[idx] = v1;
  max1[idx] = v2;
  const int b = m & 127, cc = m >> 7;
  if (b == a) didx[(cc << 7) + b] = i1;
}

// ---------------------------------------------------------------------------
// Kernel 3: gather selected[c][b][:] = vis[b, diag_idx[c][b], :]
// ---------------------------------------------------------------------------
__global__ void gather_sel(const float* __restrict__ vis,
                           const int* __restrict__ didx,
                           float* __restrict__ sel) {
  const int cb = blockIdx.x;           // c*128 + b
  const int b = cb & 127;
  const int v = didx[cb];
  const float4* src = (const float4*)(vis + ((size_t)b * V_ + v) * D_);
  float4* dst = (float4*)(sel + (size_t)cb * D_);
  dst[threadIdx.x] = src[threadIdx.x]; // 128 threads x float4 = 512 floats
}

// ---------------------------------------------------------------------------
// Half-block (128-thread) reductions inside a 256-thread block.
// Half rr = t>>7 covers threads rr*128..rr*128+127 (waves 2rr, 2rr+1).
// ---------------------------------------------------------------------------
__device__ __forceinline__ float wsum64(float v) {
  #pragma unroll
  for (int m = 32; m >= 1; m >>= 1) v += __shfl_xor(v, m);
  return v;
}
__device__ __forceinline__ float wmax64(float v) {
  #pragma unroll
  for (int m = 32; m >= 1; m >>= 1) v = fmaxf(v, __shfl_xor(v, m));
  return v;
}
__device__ __forceinline__ float halfsum(float v, float* sb, int rr, int t) {
  v = wsum64(v);
  __syncthreads();
  if ((t & 63) == 0) sb[t >> 6] = v;
  __syncthreads();
  return sb[rr * 2] + sb[rr * 2 + 1];
}
__device__ __forceinline__ float halfmax(float v, float* sb, int rr, int t) {
  v = wmax64(v);
  __syncthreads();
  if ((t & 63) == 0) sb[t >> 6] = v;
  __syncthreads();
  return fmaxf(sb[rr * 2], sb[rr * 2 + 1]);
}

// ---------------------------------------------------------------------------
// Kernel 4: fused small-GEMM rows + row losses. Block (i-pair, c): 256 thr
// = (rr: row i0+rr) x (j 0..127). Computes lan_adj/img_adj/logits elements
// in registers (K=512 fp32 dots), then CE term, score row, loss_fns row.
// acc: [0..2]=ce_sum, [3..5]=fns_sum (pair sums come from kernel 5).
// ---------------------------------------------------------------------------
__global__ __launch_bounds__(256)
void adj_losses(const float* __restrict__ lan, const float* __restrict__ sel,
                const float* __restrict__ max0, const float* __restrict__ max1,
                float* __restrict__ score, float* __restrict__ acc) {
  __shared__ float sb[4];
  __shared__ float sdiag[2];
  const int c = blockIdx.y;
  const int t = threadIdx.x;
  const int rr = t >> 7, j = t & 127;
  const int i = blockIdx.x * 2 + rr;

  const float4* xl = (const float4*)(lan + (size_t)(i * 3 + c) * D_);
  const float4* xs = (const float4*)(sel + ((size_t)c * B_ + i) * D_);
  const float4* yl = (const float4*)(lan + (size_t)(j * 3 + c) * D_);
  const float4* ys = (const float4*)(sel + ((size_t)c * B_ + j) * D_);
  float sll = 0.f, sss = 0.f, ssl = 0.f;
  #pragma unroll 4
  for (int k = 0; k < D_ / 4; ++k) {
    const float4 A = xl[k], Bv = yl[k], C = xs[k], Dv = ys[k];
    sll += A.x * Bv.x + A.y * Bv.y + A.z * Bv.z + A.w * Bv.w;
    sss += C.x * Dv.x + C.y * Dv.y + C.z * Dv.z + C.w * Dv.w;
    ssl += C.x * Bv.x + C.y * Bv.y + C.z * Bv.z + C.w * Bv.w;
  }
  const float u = 0.5f * (sll + sss);   // (lan_adj + img_adj)/2
  const float g = ssl;                  // logits

  const size_t row = ((size_t)c * B_ + i) * B_;
  const float m0 = max0[row + j];
  const float m1 = (j == i) ? -INFINITY : max1[row + j];
  if (j == i) sdiag[rr] = m0;

  // CE over [max0 row ; max1 row \ diag] (255 logits, target = diag)
  const float rmax = halfmax(fmaxf(m0, m1), sb, rr, t);
  const float se =
      halfsum(expf(m0 - rmax) + ((j == i) ? 0.f : expf(m1 - rmax)), sb, rr, t);
  if (j == 0) atomicAdd(&acc[c], logf(se) + rmax - sdiag[rr]);

  // score = row softmax of max0
  const float smax = halfmax(m0, sb, rr, t);
  const float e0 = expf(m0 - smax);
  const float ssum = halfsum(e0, sb, rr, t);
  score[row + j] = e0 / ssum;

  // loss_fns row: |softmax(u) - softmax(g)|
  const float umax = halfmax(u, sb, rr, t);
  const float eu = expf(u - umax);
  const float usum = halfsum(eu, sb, rr, t);
  const float gmax = halfmax(g, sb, rr, t);
  const float eg = expf(g - gmax);
  const float gsum = halfsum(eg, sb, rr, t);
  const float dsum = halfsum(fabsf(eu / usum - eg / gsum), sb, rr, t);
  if (j == 0) atomicAdd(&acc[3 + c], dsum);
}

// ---------------------------------------------------------------------------
// Kernel 5: pair regularization + final scalar assembly. ONE 1024-thread block.
// ---------------------------------------------------------------------------
__global__ __launch_bounds__(1024)
void pair_finalize(const float* __restrict__ score, const float* __restrict__ acc,
                   float* __restrict__ out) {
  __shared__ float diag[M_];
  __shared__ float sb[16];
  const int t = threadIdx.x;
  if (t < M_) diag[t] = score[(size_t)t * 128 + (t & 127)];
  __syncthreads();

  float gtot = 0.f;   // meaningful on thread 0 only
  #pragma unroll
  for (int c = 0; c < 3; ++c) {
    float t1 = 0.f, t2 = 0.f;
    const float* S = score + (size_t)c * (B_ * B_);
    const float* Dg = diag + c * B_;
    #pragma unroll
    for (int it = 0; it < 16; ++it) {
      const int ij = it * 1024 + t;     // 0..16383
      const int i = ij >> 7, j = ij & 127;
      if (i != j) {
        const float sij = S[i * B_ + j], sji = S[j * B_ + i];
        const float dii = Dg[i], djj = Dg[j];
        t1 += fabsf(dii - sji - djj + sij);
        t2 += fabsf(dii - sij - djj + sji);
      }
    }
    t1 = wsum64(t1);
    t2 = wsum64(t2);
    __syncthreads();
    if ((t & 63) == 0) sb[t >> 6] = t1;
    __syncthreads();
    float r1 = 0.f, r2 = 0.f;
    if (t == 0) {
      #pragma unroll
      for (int w = 0; w < 16; ++w) r1 += sb[w];
    }
    __syncthreads();
    if ((t & 63) == 0) sb[t >> 6] = t2;
    __syncthreads();
    if (t == 0) {
      #pragma unroll
      for (int w = 0; w < 16; ++w) r2 += sb[w];
      const float den = (float)(B_ * (B_ - 1));
      const float ce = acc[c] / (float)B_;
      const float fns = acc[3 + c] / (float)(B_ * B_);
      gtot += ce + 0.1f * fns +
              0.1f * (fmaxf(r1 / den, 0.f) + fmaxf(r2 / den, 0.f));
    }
    __syncthreads();
  }
  if (t == 0) out[0] = gtot / 3.f;
}

// ---------------------------------------------------------------------------
extern "C" void kernel_launch(void* const* d_in, const int* in_sizes, int n_in,
                              void* d_out, int out_size, void* d_ws, size_t ws_size,
                              hipStream_t stream) {
  const float* vis = (const float*)d_in[0];  // [128][784][512]
  const float* lan = (const float*)d_in[1];  // [128][3][512]
  float* out = (float*)d_out;

  // Workspace layout (float-equivalents). Total ~= 6.3 MB.
  float* w = (float*)d_ws;
  float* pv1 = w;                                   // [128 a][7 nch][384 m]
  float* pv2 = pv1 + (size_t)M_ * B_ * NCH;
  int*   pi1 = (int*)(pv2 + (size_t)M_ * B_ * NCH);
  float* max0 = (float*)(pi1 + (size_t)M_ * B_ * NCH);  // [3][128][128]
  float* max1 = max0 + 3 * B_ * B_;
  int*   didx = (int*)(max1 + 3 * B_ * B_);             // [3][128]
  float* sel  = (float*)(didx + 3 * B_);                // [3][128][512]
  float* score = sel + (size_t)3 * B_ * D_;             // [3][128][128]
  float* acc   = score + 3 * B_ * B_;                   // 12 floats (+pad)
  ushort* lanbf = (ushort*)(acc + 16);                  // 393216 ushorts

  prep_lan<<<dim3(48), dim3(256), 0, stream>>>(lan, lanbf, acc);
  gemm_top2<<<dim3(B_ * NCH), dim3(512), 0, stream>>>(vis, lanbf, pv1, pv2, pi1);
  reduce_top2<<<dim3((M_ * B_ + 255) / 256), dim3(256), 0, stream>>>(
      pv1, pv2, pi1, max0, max1, didx);
  gather_sel<<<dim3(3 * B_), dim3(128), 0, stream>>>(vis, didx, sel);
  adj_losses<<<dim3(B_ / 2, 3), dim3(256), 0, stream>>>(
      lan, sel, max0, max1, score, acc);
  pair_finalize<<<dim3(1), dim3(1024), 0, stream>>>(score, acc, out);
}

// Round 7
// 481.600 us; speedup vs baseline: 1.3428x; 1.1048x over previous
//
#include <hip/hip_runtime.h>
#include <math.h>

// Problem constants (B=128, V=784, D=512, 3 cases)
#define B_   128
#define V_   784
#define D_   512
#define M_   384      // 3*B rows (case-major: m = c*128 + b)
#define NCH  7        // ceil(784/128) column chunks

typedef __attribute__((ext_vector_type(8))) short short8;   // 8 bf16 (4 VGPRs)
typedef __attribute__((ext_vector_type(4))) float f32x4;    // MFMA accumulator
typedef unsigned int u32t;

// fp32 -> bf16 round-to-nearest-even (finite inputs)
__device__ __forceinline__ ushort f2bf(float x) {
  uint u = __float_as_uint(x);
  u += 0x7fff + ((u >> 16) & 1);
  return (ushort)(u >> 16);
}
__device__ __forceinline__ float bf2f(ushort h) {
  return __uint_as_float((uint)h << 16);
}

// global -> LDS direct: 16B/lane; LDS dest = wave-uniform base + lane*16 (HW),
// global source is per-lane. (Verified working in round 5.)
__device__ __forceinline__ void stage16(const void* g, void* l) {
  __builtin_amdgcn_global_load_lds(
      (const __attribute__((address_space(1))) u32t*)g,
      (__attribute__((address_space(3))) u32t*)(uintptr_t)l, 16, 0, 0);
}

// ---------------------------------------------------------------------------
// Kernel 0: lan -> bf16 hi/lo, fragment-linear 1KB chunks (c,s,h,m16):
//   byte off = ((c*16+s)*2 + h)*8192 + m16*1024 + lane*16
//   lane=(tx,qq): element (row b = m16*16+tx, k = s*32 + qq*8 + e)
// (Same layout as round 5 - verified.) Block 0 zeroes the 12 accumulators.
// ---------------------------------------------------------------------------
__global__ __launch_bounds__(256)
void prep_lan(const float* __restrict__ lan, ushort* __restrict__ lanbf,
              float* __restrict__ acc) {
  const int c = blockIdx.x >> 4, s = blockIdx.x & 15, t = threadIdx.x;
  if (blockIdx.x == 0 && t < 12) acc[t] = 0.f;
  #pragma unroll
  for (int it = 0; it < 2; ++it) {
    const int u = t + it * 256;          // 0..511 = m16*64 + lane
    const int m16 = u >> 6, lane = u & 63;
    const int row = m16 * 16 + (lane & 15);
    const int k = s * 32 + (lane >> 4) * 8;
    const float* src = lan + (size_t)(row * 3 + c) * D_ + k;
    const float4 v0 = *(const float4*)src;
    const float4 v1 = *(const float4*)(src + 4);
    union { ushort s[8]; uint4 q; } H, L;
    const float f[8] = {v0.x, v0.y, v0.z, v0.w, v1.x, v1.y, v1.z, v1.w};
    #pragma unroll
    for (int e = 0; e < 8; ++e) {
      const ushort h = f2bf(f[e]);
      H.s[e] = h; L.s[e] = f2bf(f[e] - bf2f(h));
    }
    const size_t base = ((size_t)(c * 16 + s) * 2) * 4096;   // ushort units
    *(uint4*)&lanbf[base + (size_t)m16 * 512 + lane * 8] = H.q;        // h=0
    *(uint4*)&lanbf[base + 4096 + (size_t)m16 * 512 + lane * 8] = L.q; // h=1
  }
}

// convert 8 staged fp32 -> hi/lo bf16 chunks, write to Bbf region
__device__ __forceinline__ void cvt_write(char* base, int t,
                                          float4 b0, float4 b1) {
  union { ushort s[8]; uint4 q; } H, L;
  const float f[8] = {b0.x, b0.y, b0.z, b0.w, b1.x, b1.y, b1.z, b1.w};
  #pragma unroll
  for (int e = 0; e < 8; ++e) {
    const ushort h = f2bf(f[e]);
    H.s[e] = h; L.s[e] = f2bf(f[e] - bf2f(h));
  }
  *(uint4*)(base + t * 16) = H.q;
  *(uint4*)(base + 8192 + t * 16) = L.q;
}

// ---------------------------------------------------------------------------
// Kernel 1: sim GEMM, 3-case fused, fused top-2. Block (a,nch), 512 thr,
// 8 waves = 4 wr (32 rows) x 2 wc (64 cols). 16 K-steps of 32.
// A: global_load_lds -> 2x48KB LDS dbuf (1KB chunks, linear).
// B: global->reg (2x dwordx4, last in vmcnt FIFO) -> convert ONCE ->
//    ds_write bf16 hi/lo -> 2x16KB LDS dbuf. One __syncthreads per step;
//    its vmcnt(0) lands ~2800 cyc after stage issue -> no exposed latency.
// All LDS accesses: every 16-lane phase reads/writes 256B contiguous -> no
// bank conflicts. S = Ah*Bh + Ah*Bl + Al*Bh (fp32-accurate to ~2^-18).
// ---------------------------------------------------------------------------
__global__ __launch_bounds__(512, 2)
void gemm_top2(const float* __restrict__ vis, const ushort* __restrict__ lanbf,
               float* __restrict__ pv1, float* __restrict__ pv2,
               int* __restrict__ pi1) {
  __shared__ __align__(16) char Lds[131072];   // A 2x48K | B 2x16K

  const int id = blockIdx.x;     // 0..895
  const int a = id / NCH;
  const int nch = id - NCH * a;
  const int t = threadIdx.x;
  const int lane = t & 63, wid = t >> 6;
  const int tx = lane & 15, qq = lane >> 4;
  const int wr = wid >> 1, wc = wid & 1;
  const int v0 = nch * 128;

  // A-stage sources: 6 per wave, chunk j = wid*6+q -> (c=j>>4, h=(j>>3)&1, m16=j&7)
  const char* asrc[6];
  #pragma unroll
  for (int q = 0; q < 6; ++q) {
    const int j = wid * 6 + q;
    const int c = j >> 4, h = (j >> 3) & 1, m16 = j & 7;
    asrc[q] = (const char*)lanbf + (size_t)c * 262144 + h * 8192 + m16 * 1024 +
              lane * 16;
  }
  // B source: thread t covers (row v0 + (t&127), k-quarter t>>7)
  int vrow = v0 + (t & 127);
  if (vrow > V_ - 1) vrow = V_ - 1;   // clamp (cols >= V_ masked in epilogue)
  const float* bsrc = vis + (size_t)a * (V_ * D_) + (size_t)vrow * D_ + (t >> 7) * 8;

  f32x4 acc[3][2][4];
  const f32x4 zz = {0.f, 0.f, 0.f, 0.f};
  #pragma unroll
  for (int c = 0; c < 3; ++c)
    #pragma unroll
    for (int m = 0; m < 2; ++m)
      #pragma unroll
      for (int n = 0; n < 4; ++n) acc[c][m][n] = zz;

  // prologue: stage A(0) + B(0)
  #pragma unroll
  for (int q = 0; q < 6; ++q)
    stage16(asrc[q], Lds + (wid * 6 + q) * 1024);
  {
    const float4 b0 = *(const float4*)bsrc;
    const float4 b1 = *(const float4*)(bsrc + 4);
    cvt_write(Lds + 98304, t, b0, b1);
  }
  __syncthreads();

  for (int s = 0; s < 16; ++s) {
    const int p = s & 1;
    const char* Ap = Lds + p * 49152;
    const char* Bp = Lds + 98304 + p * 16384;
    float4 b0, b1;
    if (s < 15) {   // issue next-step stages FIRST (land under the MFMAs)
      char* An = Lds + (p ^ 1) * 49152;
      #pragma unroll
      for (int q = 0; q < 6; ++q)
        stage16(asrc[q] + (size_t)(s + 1) * 16384, An + (wid * 6 + q) * 1024);
      b0 = *(const float4*)(bsrc + (s + 1) * 32);
      b1 = *(const float4*)(bsrc + (s + 1) * 32 + 4);
    }
    // ---- compute step s ----
    short8 bh[4], bl[4];
    #pragma unroll
    for (int n = 0; n < 4; ++n) {
      const int ch = qq * 128 + (wc * 4 + n) * 16 + tx;   // writer thread id
      bh[n] = *(const short8*)(Bp + ch * 16);
      bl[n] = *(const short8*)(Bp + 8192 + ch * 16);
    }
    #pragma unroll
    for (int c = 0; c < 3; ++c) {
      short8 ah[2], al[2];
      #pragma unroll
      for (int m = 0; m < 2; ++m) {
        ah[m] = *(const short8*)(Ap + (c * 16 + wr * 2 + m) * 1024 + lane * 16);
        al[m] = *(const short8*)(Ap + (c * 16 + 8 + wr * 2 + m) * 1024 + lane * 16);
      }
      #pragma unroll
      for (int m = 0; m < 2; ++m)
        #pragma unroll
        for (int n = 0; n < 4; ++n) {
          acc[c][m][n] = __builtin_amdgcn_mfma_f32_16x16x32_bf16(
              ah[m], bh[n], acc[c][m][n], 0, 0, 0);
          acc[c][m][n] = __builtin_amdgcn_mfma_f32_16x16x32_bf16(
              ah[m], bl[n], acc[c][m][n], 0, 0, 0);
          acc[c][m][n] = __builtin_amdgcn_mfma_f32_16x16x32_bf16(
              al[m], bh[n], acc[c][m][n], 0, 0, 0);
        }
    }
    if (s < 15)   // convert + write B(s+1) after compute (T14 write-late)
      cvt_write(Lds + 98304 + (p ^ 1) * 16384, t, b0, b1);
    __syncthreads();
  }

  // Epilogue: per-case top-2 (round-5-verified layout).
  // row(b) = wr*32 + m*16 + qq*4 + r; col(v) = v0 + wc*64 + n*16 + tx.
  float* p1b = (float*)Lds;            // scratch in A region
  float* p2b = p1b + 256;
  int*   i1b = (int*)(p2b + 256);
  #pragma unroll
  for (int c = 0; c < 3; ++c) {
    #pragma unroll
    for (int m = 0; m < 2; ++m)
      #pragma unroll
      for (int r = 0; r < 4; ++r) {
        float v1 = -INFINITY, v2 = -INFINITY;
        int i1 = 0x7fffffff;
        #pragma unroll
        for (int n = 0; n < 4; ++n) {
          const int vv = v0 + wc * 64 + n * 16 + tx;
          const float x = acc[c][m][n][r];
          if (vv < V_) {
            if (x > v1) { v2 = v1; v1 = x; i1 = vv; }
            else if (x > v2) { v2 = x; }
          }
        }
        #pragma unroll
        for (int off = 8; off >= 1; off >>= 1) {
          const float ov1 = __shfl_xor(v1, off, 16);
          const float ov2 = __shfl_xor(v2, off, 16);
          const int   oi1 = __shfl_xor(i1, off, 16);
          if (ov1 > v1 || (ov1 == v1 && oi1 < i1)) {
            v2 = fmaxf(v1, ov2); v1 = ov1; i1 = oi1;
          } else {
            v2 = fmaxf(v2, ov1);
          }
        }
        if (tx == 0) {
          const int grow = wr * 32 + m * 16 + qq * 4 + r;
          p1b[wc * 128 + grow] = v1;
          p2b[wc * 128 + grow] = v2;
          i1b[wc * 128 + grow] = i1;
        }
      }
    __syncthreads();
    if (t < 128) {   // merge wc halves (wc0 = smaller v: tie keeps smaller idx)
      float v1 = p1b[t], v2 = p2b[t];
      int i1 = i1b[t];
      const float ov1 = p1b[128 + t], ov2 = p2b[128 + t];
      const int oi1 = i1b[128 + t];
      if (ov1 > v1) { v2 = fmaxf(v1, ov2); v1 = ov1; i1 = oi1; }
      else          { v2 = fmaxf(v2, ov1); }
      const size_t o = ((size_t)a * NCH + nch) * M_ + c * B_ + t;
      pv1[o] = v1; pv2[o] = v2; pi1[o] = i1;
    }
    __syncthreads();
  }
}

// ---------------------------------------------------------------------------
// Kernel 2: merge the 7 chunk-partials. Block = a (128), thread = m (384):
// reads (a*7+nc)*384 + m are COALESCED in m (round-5 version was stride-10.5KB).
// ---------------------------------------------------------------------------
__global__ __launch_bounds__(384)
void reduce_top2(const float* __restrict__ pv1,
                 const float* __restrict__ pv2,
                 const int* __restrict__ pi1,
                 float* __restrict__ max0, float* __restrict__ max1,
                 int* __restrict__ didx) {
  const int a = blockIdx.x, m = threadIdx.x;
  float v1 = -INFINITY, v2 = -INFINITY;
  int i1 = 0x7fffffff;
  #pragma unroll
  for (int nc = 0; nc < NCH; nc++) {
    const size_t o = ((size_t)a * NCH + nc) * M_ + m;
    const float ov1 = pv1[o], ov2 = pv2[o];
    const int oi1 = pi1[o];
    if (ov1 > v1 || (ov1 == v1 && oi1 < i1)) {
      v2 = fmaxf(v1, ov2); v1 = ov1; i1 = oi1;
    } else {
      v2 = fmaxf(v2, ov1);
    }
  }
  max0[(size_t)m * B_ + a] = v1;
  max1[(size_t)m * B_ + a] = v2;
  const int b = m & 127, cc = m >> 7;
  if (b == a) didx[cc * B_ + b] = i1;
}

// ---------------------------------------------------------------------------
// Kernel 3: gather selected[c][b][:] = vis[b, diag_idx[c][b], :]
// ---------------------------------------------------------------------------
__global__ void gather_sel(const float* __restrict__ vis,
                           const int* __restrict__ didx,
                           float* __restrict__ sel) {
  const int cb = blockIdx.x;           // c*128 + b
  const int b = cb & 127;
  const int v = didx[cb];
  const float4* src = (const float4*)(vis + ((size_t)b * V_ + v) * D_);
  float4* dst = (float4*)(sel + (size_t)cb * D_);
  dst[threadIdx.x] = src[threadIdx.x];
}

// ---------------------------------------------------------------------------
// Full 256-thread block reductions (4 waves).
// ---------------------------------------------------------------------------
__device__ __forceinline__ float wsum64(float v) {
  #pragma unroll
  for (int m = 32; m >= 1; m >>= 1) v += __shfl_xor(v, m);
  return v;
}
__device__ __forceinline__ float wmax64(float v) {
  #pragma unroll
  for (int m = 32; m >= 1; m >>= 1) v = fmaxf(v, __shfl_xor(v, m));
  return v;
}
__device__ __forceinline__ float bsum4(float v, float* sb, int t) {
  v = wsum64(v);
  __syncthreads();
  if ((t & 63) == 0) sb[t >> 6] = v;
  __syncthreads();
  return sb[0] + sb[1] + sb[2] + sb[3];
}
__device__ __forceinline__ float bmax4(float v, float* sb, int t) {
  v = wmax64(v);
  __syncthreads();
  if ((t & 63) == 0) sb[t >> 6] = v;
  __syncthreads();
  return fmaxf(fmaxf(sb[0], sb[1]), fmaxf(sb[2], sb[3]));
}

// ---------------------------------------------------------------------------
// Kernel 4: fused adj rows + row losses. Block (i, c), 256 thr = (j, khalf h).
// Row-i operands staged in LDS; K split across h (2x shorter dot chain);
// full-dot via shfl_xor(.,1). Block-wide sums count each j twice -> x0.5.
// acc: [0..2]=ce_sum, [3..5]=fns_sum.
// ---------------------------------------------------------------------------
__global__ __launch_bounds__(256)
void adj_losses(const float* __restrict__ lan, const float* __restrict__ sel,
                const float* __restrict__ max0, const float* __restrict__ max1,
                float* __restrict__ score, float* __restrict__ acc) {
  __shared__ float4 xls[128], xss[128];
  __shared__ float sb[4];
  __shared__ float sdiag;
  const int c = blockIdx.y, i = blockIdx.x;
  const int t = threadIdx.x;
  const int j = t >> 1, h = t & 1;

  if (t < 128) xls[t] = ((const float4*)(lan + (size_t)(i * 3 + c) * D_))[t];
  else xss[t - 128] = ((const float4*)(sel + ((size_t)c * B_ + i) * D_))[t - 128];
  __syncthreads();

  const float4* yl = (const float4*)(lan + (size_t)(j * 3 + c) * D_) + h * 64;
  const float4* ys = (const float4*)(sel + ((size_t)c * B_ + j) * D_) + h * 64;
  float sll = 0.f, sss = 0.f, ssl = 0.f;
  #pragma unroll 4
  for (int k = 0; k < 64; ++k) {
    const float4 A = xls[h * 64 + k], C = xss[h * 64 + k];
    const float4 Bv = yl[k], Dv = ys[k];
    sll += A.x * Bv.x + A.y * Bv.y + A.z * Bv.z + A.w * Bv.w;
    sss += C.x * Dv.x + C.y * Dv.y + C.z * Dv.z + C.w * Dv.w;
    ssl += C.x * Bv.x + C.y * Bv.y + C.z * Bv.z + C.w * Bv.w;
  }
  sll += __shfl_xor(sll, 1);
  sss += __shfl_xor(sss, 1);
  ssl += __shfl_xor(ssl, 1);
  const float u = 0.5f * (sll + sss);   // (lan_adj + img_adj)/2
  const float g = ssl;                  // logits

  const size_t row = ((size_t)c * B_ + i) * B_;
  const float m0 = max0[row + j];
  const float m1 = (j == i) ? -INFINITY : max1[row + j];
  if (j == i && h == 0) sdiag = m0;

  // CE over [max0 row ; max1 row \ diag]
  const float rmax = bmax4(fmaxf(m0, m1), sb, t);
  const float se = 0.5f *
      bsum4(expf(m0 - rmax) + ((j == i) ? 0.f : expf(m1 - rmax)), sb, t);
  if (t == 0) atomicAdd(&acc[c], logf(se) + rmax - sdiag);

  // score = row softmax of max0
  const float smax = bmax4(m0, sb, t);
  const float e0 = expf(m0 - smax);
  const float ssum = 0.5f * bsum4(e0, sb, t);
  score[row + j] = e0 / ssum;   // both h write identical value

  // loss_fns row: |softmax(u) - softmax(g)|
  const float umax = bmax4(u, sb, t);
  const float eu = expf(u - umax);
  const float usum = 0.5f * bsum4(eu, sb, t);
  const float gmax = bmax4(g, sb, t);
  const float eg = expf(g - gmax);
  const float gsum = 0.5f * bsum4(eg, sb, t);
  const float dsum = 0.5f * bsum4(fabsf(eu / usum - eg / gsum), sb, t);
  if (t == 0) atomicAdd(&acc[3 + c], dsum);
}

// ---------------------------------------------------------------------------
// Kernel 5: pair regularization + final scalar assembly. ONE 1024-thread block.
// ---------------------------------------------------------------------------
__global__ __launch_bounds__(1024)
void pair_finalize(const float* __restrict__ score, const float* __restrict__ acc,
                   float* __restrict__ out) {
  __shared__ float diag[M_];
  __shared__ float sb[16];
  const int t = threadIdx.x;
  if (t < M_) diag[t] = score[(size_t)t * 128 + (t & 127)];
  __syncthreads();

  float gtot = 0.f;
  #pragma unroll
  for (int c = 0; c < 3; ++c) {
    float t1 = 0.f, t2 = 0.f;
    const float* S = score + (size_t)c * (B_ * B_);
    const float* Dg = diag + c * B_;
    #pragma unroll
    for (int it = 0; it < 16; ++it) {
      const int ij = it * 1024 + t;
      const int i = ij >> 7, j = ij & 127;
      if (i != j) {
        const float sij = S[i * B_ + j], sji = S[j * B_ + i];
        const float dii = Dg[i], djj = Dg[j];
        t1 += fabsf(dii - sji - djj + sij);
        t2 += fabsf(dii - sij - djj + sji);
      }
    }
    t1 = wsum64(t1);
    t2 = wsum64(t2);
    __syncthreads();
    if ((t & 63) == 0) sb[t >> 6] = t1;
    __syncthreads();
    float r1 = 0.f, r2 = 0.f;
    if (t == 0) {
      #pragma unroll
      for (int w = 0; w < 16; ++w) r1 += sb[w];
    }
    __syncthreads();
    if ((t & 63) == 0) sb[t >> 6] = t2;
    __syncthreads();
    if (t == 0) {
      #pragma unroll
      for (int w = 0; w < 16; ++w) r2 += sb[w];
      const float den = (float)(B_ * (B_ - 1));
      const float ce = acc[c] / (float)B_;
      const float fns = acc[3 + c] / (float)(B_ * B_);
      gtot += ce + 0.1f * fns +
              0.1f * (fmaxf(r1 / den, 0.f) + fmaxf(r2 / den, 0.f));
    }
    __syncthreads();
  }
  if (t == 0) out[0] = gtot / 3.f;
}

// ---------------------------------------------------------------------------
extern "C" void kernel_launch(void* const* d_in, const int* in_sizes, int n_in,
                              void* d_out, int out_size, void* d_ws, size_t ws_size,
                              hipStream_t stream) {
  const float* vis = (const float*)d_in[0];  // [128][784][512]
  const float* lan = (const float*)d_in[1];  // [128][3][512]
  float* out = (float*)d_out;

  float* w = (float*)d_ws;
  float* pv1 = w;                                   // [128 a][7 nch][384 m]
  float* pv2 = pv1 + (size_t)M_ * B_ * NCH;
  int*   pi1 = (int*)(pv2 + (size_t)M_ * B_ * NCH);
  float* max0 = (float*)(pi1 + (size_t)M_ * B_ * NCH);  // [3][128 b][128 a]
  float* max1 = max0 + 3 * B_ * B_;
  int*   didx = (int*)(max1 + 3 * B_ * B_);             // [3][128]
  float* sel  = (float*)(didx + 3 * B_);                // [3][128][512]
  float* score = sel + (size_t)3 * B_ * D_;             // [3][128][128]
  float* acc   = score + 3 * B_ * B_;                   // 12 floats (+pad)
  ushort* lanbf = (ushort*)(acc + 16);                  // 393216 ushorts

  prep_lan<<<dim3(48), dim3(256), 0, stream>>>(lan, lanbf, acc);
  gemm_top2<<<dim3(B_ * NCH), dim3(512), 0, stream>>>(vis, lanbf, pv1, pv2, pi1);
  reduce_top2<<<dim3(B_), dim3(384), 0, stream>>>(
      pv1, pv2, pi1, max0, max1, didx);
  gather_sel<<<dim3(3 * B_), dim3(128), 0, stream>>>(vis, didx, sel);
  adj_losses<<<dim3(B_, 3), dim3(256), 0, stream>>>(
      lan, sel, max0, max1, score, acc);
  pair_finalize<<<dim3(1), dim3(1024), 0, stream>>>(score, acc, out);
}